// Round 14
// baseline (59.669 us; speedup 1.0000x reference)
//
#include <hip/hip_runtime.h>
#include <math.h>

constexpr int H = 1024;
constexpr int V = 50257;
constexpr int L = 64;

constexpr int NBLKD = 512;             // out-proj blocks (2/CU, one generation)

// ws float offsets
constexpr int OFF_ALOG = 0;            // 64 attention logits
constexpr int OFF_GH   = 64;           // 3072: gh = w_hh@h0 + b_hh
constexpr int OFF_CP   = 64 + 3 * H;   // 1024: comb emb-half partial
constexpr int OFF_X    = OFF_CP + H;   // 1024: x = relu(comb)
constexpr int OFF_LOG  = OFF_X + H;    // V logits
constexpr int OFF_PAIR = OFF_LOG + V;  // 2*NBLKD (m,s) pairs

typedef float f32x4 __attribute__((ext_vector_type(4)));

__device__ __forceinline__ float wsum(float v) {
#pragma unroll
    for (int off = 32; off > 0; off >>= 1) v += __shfl_xor(v, off);
    return v;
}
__device__ __forceinline__ float wmax(float v) {
#pragma unroll
    for (int off = 32; off > 0; off >>= 1) v = fmaxf(v, __shfl_xor(v, off));
    return v;
}

__device__ __forceinline__ float dot4(float4 a, float4 b) {
    return a.x * b.x + a.y * b.y + a.z * b.z + a.w * b.w;
}
__device__ __forceinline__ float dot4v(f32x4 a, f32x4 b) {
    return a.x * b.x + a.y * b.y + a.z * b.z + a.w * b.w;
}

__device__ __forceinline__ float dotN(const float* __restrict__ w,
                                      const float* __restrict__ v,
                                      int lane, int n4) { // n4 = N/256
    const float4* w4 = reinterpret_cast<const float4*>(w);
    const float4* v4 = reinterpret_cast<const float4*>(v);
    float acc = 0.f;
    for (int it = 0; it < n4; ++it)
        acc += dot4(w4[lane + it * 64], v4[lane + it * 64]);
    return acc;
}

__device__ __forceinline__ void msmerge(float& m, float& s, float m2, float s2) {
    const float M = fmaxf(m, m2);
    s = s * expf(m - M) + s2 * expf(m2 - M);
    m = M;
}

// ---- A: logits (blocks 0..63) || gh (64..831) || comb-emb-half (832..1087) -
__global__ __launch_bounds__(256) void kA(const long long* __restrict__ idx_p,
                                          const float* __restrict__ hid,
                                          const float* __restrict__ emb,
                                          const float* __restrict__ attn_W,
                                          const float* __restrict__ attn_b,
                                          const float* __restrict__ w_hh,
                                          const float* __restrict__ b_hh,
                                          const float* __restrict__ comb_W,
                                          float* __restrict__ ws) {
    const int tid = threadIdx.x;
    const int lane = tid & 63, wid = tid >> 6;
    const int b = blockIdx.x;
    if (b < 64) {
        const int l = b;
        const int idx = (int)idx_p[0];
        const float4* w4 = reinterpret_cast<const float4*>(attn_W + (size_t)l * (2 * H));
        const float4* e4 = reinterpret_cast<const float4*>(emb + (size_t)idx * H);
        const float4* h4 = reinterpret_cast<const float4*>(hid);
        float acc = dot4(w4[tid], e4[tid]) + dot4(w4[tid + 256], h4[tid]);
        acc = wsum(acc);
        __shared__ float sred[4];
        if (lane == 0) sred[wid] = acc;
        __syncthreads();
        if (tid == 0)
            ws[OFF_ALOG + l] = sred[0] + sred[1] + sred[2] + sred[3] + attn_b[l];
    } else if (b < 832) {
        __shared__ __align__(16) float4 sv[256];
        sv[tid] = reinterpret_cast<const float4*>(hid)[tid];
        __syncthreads();
        const int row = (b - 64) * 4 + wid;  // 0..3071
        float acc = wsum(dotN(w_hh + (size_t)row * H,
                              reinterpret_cast<const float*>(sv), lane, 4));
        if (lane == 0) ws[OFF_GH + row] = acc + b_hh[row];
    } else {
        __shared__ __align__(16) float4 se[256];
        const int idx = (int)idx_p[0];
        se[tid] = reinterpret_cast<const float4*>(emb + (size_t)idx * H)[tid];
        __syncthreads();
        const int row = (b - 832) * 4 + wid;  // 0..1023
        float acc = wsum(dotN(comb_W + (size_t)row * (2 * H),
                              reinterpret_cast<const float*>(se), lane, 4));
        if (lane == 0) ws[OFF_CP + row] = acc;   // no bias yet
    }
}

// ---- B: softmax + attn_applied + comb-attn-half -> x (256 blocks) ---------
__global__ __launch_bounds__(256) void kB(const float* __restrict__ enc,
                                          const float* __restrict__ comb_W,
                                          const float* __restrict__ comb_b,
                                          float* __restrict__ ws,
                                          float* __restrict__ out) {
    __shared__ float wls[L];
    __shared__ __align__(16) float4 sx[256];  // attn_applied
    const int tid = threadIdx.x;
    if (tid < L) {
        const float lg = ws[OFF_ALOG + tid];   // wave 0 holds all 64 logits
        const float m = wmax(lg);
        const float e = expf(lg - m);
        const float s = wsum(e);
        wls[tid] = e / s;
        if (blockIdx.x == 0) out[V + H + tid] = e / s;
    }
    __syncthreads();
    {
        const float4* e4 = reinterpret_cast<const float4*>(enc);
        float4 a4 = {0.f, 0.f, 0.f, 0.f};
#pragma unroll 8
        for (int l = 0; l < L; ++l) {
            const float wl = wls[l];
            const float4 v = e4[l * 256 + tid];
            a4.x += wl * v.x; a4.y += wl * v.y;
            a4.z += wl * v.z; a4.w += wl * v.w;
        }
        sx[tid] = a4;
    }
    __syncthreads();
    const int lane = tid & 63, wid = tid >> 6;
    const int row = blockIdx.x * 4 + wid;  // 0..1023
    float acc = wsum(dotN(comb_W + (size_t)row * (2 * H) + H,
                          reinterpret_cast<const float*>(sx), lane, 4));
    if (lane == 0)
        ws[OFF_X + row] = fmaxf(acc + ws[OFF_CP + row] + comb_b[row], 0.f);
}

// ---- C: gi GEMV + GRU gates fused (256 blocks x 768 threads) --------------
__global__ __launch_bounds__(768) void kC(const float* __restrict__ w_ih,
                                          const float* __restrict__ b_ih,
                                          const float* __restrict__ hid,
                                          float* __restrict__ ws,
                                          float* __restrict__ out) {
    __shared__ __align__(16) float4 sx4[256];  // x
    __shared__ float gi_s[12];
    const int tid = threadIdx.x;
    if (tid < 256) sx4[tid] = reinterpret_cast<const float4*>(ws + OFF_X)[tid];
    __syncthreads();
    const int lane = tid & 63, wid = tid >> 6;  // wid 0..11
    const int g = wid >> 2, i = wid & 3;
    const int row = g * H + blockIdx.x * 4 + i;
    float acc = wsum(dotN(w_ih + (size_t)row * H,
                          reinterpret_cast<const float*>(sx4), lane, 4));
    if (lane == 0) gi_s[wid] = acc + b_ih[row];
    __syncthreads();
    if (tid < 4) {
        const int t = blockIdx.x * 4 + tid;
        const float ir = gi_s[tid], iz = gi_s[4 + tid], in_ = gi_s[8 + tid];
        const float hr = ws[OFF_GH + t];
        const float hz = ws[OFF_GH + H + t];
        const float hn = ws[OFF_GH + 2 * H + t];
        const float r = 1.f / (1.f + expf(-(ir + hr)));
        const float z = 1.f / (1.f + expf(-(iz + hz)));
        const float n = tanhf(in_ + r * hn);
        out[V + t] = (1.f - z) * n + z * hid[t];
    }
}

// ---- D: out-proj GEMV. reg h_new, 2-row pairs, NT loads, 2-deep prefetch --
__global__ __launch_bounds__(512, 4) void kD(const float* __restrict__ out_W,
                                             const float* __restrict__ out_b,
                                             const float* __restrict__ hnew,
                                             float* __restrict__ ws) {
    __shared__ float lds_log[104];
    const int tid = threadIdx.x, lane = tid & 63, wid = tid >> 6;  // 8 waves
    const int b = blockIdx.x;
    const int row0 = (int)(((long long)b * V) / NBLKD);
    const int row1 = (int)(((long long)(b + 1) * V) / NBLKD);
    const int nrows = row1 - row0;    // 98 or 99
    const int kmax = nrows - 1;
    // h_new fragment per lane: 16 VGPRs, loaded once (L2/L3 serves duplicates)
    const f32x4* v4 = reinterpret_cast<const f32x4*>(hnew);
    const f32x4 hv0 = v4[lane], hv1 = v4[lane + 64];
    const f32x4 hv2 = v4[lane + 128], hv3 = v4[lane + 192];

#define ROWP(kk) reinterpret_cast<const f32x4*>( \
        out_W + (size_t)(row0 + min((kk), kmax)) * H)
    const f32x4* p0 = ROWP(2 * wid);
    const f32x4* p1 = ROWP(2 * wid + 1);
    f32x4 A0 = __builtin_nontemporal_load(p0 + lane);
    f32x4 A1 = __builtin_nontemporal_load(p0 + lane + 64);
    f32x4 A2 = __builtin_nontemporal_load(p0 + lane + 128);
    f32x4 A3 = __builtin_nontemporal_load(p0 + lane + 192);
    f32x4 B0 = __builtin_nontemporal_load(p1 + lane);
    f32x4 B1 = __builtin_nontemporal_load(p1 + lane + 64);
    f32x4 B2 = __builtin_nontemporal_load(p1 + lane + 128);
    f32x4 B3 = __builtin_nontemporal_load(p1 + lane + 192);

    for (int k = 2 * wid; k < nrows; k += 16) {
        // prefetch next pair (clamped at tail; few wasted loads)
        const f32x4* q0 = ROWP(k + 16);
        const f32x4* q1 = ROWP(k + 17);
        const f32x4 N0 = __builtin_nontemporal_load(q0 + lane);
        const f32x4 N1 = __builtin_nontemporal_load(q0 + lane + 64);
        const f32x4 N2 = __builtin_nontemporal_load(q0 + lane + 128);
        const f32x4 N3 = __builtin_nontemporal_load(q0 + lane + 192);
        const f32x4 M0 = __builtin_nontemporal_load(q1 + lane);
        const f32x4 M1 = __builtin_nontemporal_load(q1 + lane + 64);
        const f32x4 M2 = __builtin_nontemporal_load(q1 + lane + 128);
        const f32x4 M3 = __builtin_nontemporal_load(q1 + lane + 192);
        // compute current pair
        float s0 = dot4v(A0, hv0) + dot4v(A1, hv1) + dot4v(A2, hv2) + dot4v(A3, hv3);
        float s1 = dot4v(B0, hv0) + dot4v(B1, hv1) + dot4v(B2, hv2) + dot4v(B3, hv3);
        s0 = wsum(s0); s1 = wsum(s1);
        if (lane == 0) {
            lds_log[k] = s0 + out_b[row0 + k];
            if (k + 1 < nrows) lds_log[k + 1] = s1 + out_b[row0 + k + 1];
        }
        A0 = N0; A1 = N1; A2 = N2; A3 = N3;
        B0 = M0; B1 = M1; B2 = M2; B3 = M3;
    }
#undef ROWP
    __syncthreads();
    // coalesced logits write
    for (int i = tid; i < nrows; i += 512)
        ws[OFF_LOG + row0 + i] = lds_log[i];
    if (wid == 0) {  // block (m,s) partial over nrows (<= 99)
        float v0 = (lane < nrows) ? lds_log[lane] : -INFINITY;
        float v1 = (64 + lane < nrows) ? lds_log[64 + lane] : -INFINITY;
        const float m = wmax(fmaxf(v0, v1));
        float e = 0.f;
        if (lane < nrows)      e += expf(v0 - m);
        if (64 + lane < nrows) e += expf(v1 - m);
        const float s = wsum(e);
        if (lane == 0) {
            ws[OFF_PAIR + 2 * b] = m;
            ws[OFF_PAIR + 2 * b + 1] = s;
        }
    }
}

// ---- E: redundant (m,s) combine per block + log-softmax write -------------
__global__ __launch_bounds__(256) void kE(const float* __restrict__ ws,
                                          float* __restrict__ out) {
    const int tid = threadIdx.x, lane = tid & 63, wid = tid >> 6;
    float m = -INFINITY, s = 0.f;
    for (int i = tid; i < NBLKD; i += 256) {  // 2 iterations
        const float mi = ws[OFF_PAIR + 2 * i];
        const float si = ws[OFF_PAIR + 2 * i + 1];
        if (si > 0.f) msmerge(m, s, mi, si);
    }
#pragma unroll
    for (int off = 32; off > 0; off >>= 1) {
        const float mo = __shfl_xor(m, off);
        const float so = __shfl_xor(s, off);
        if (so > 0.f) msmerge(m, s, mo, so);
    }
    __shared__ float sm[4], ss[4], fin[2];
    if (lane == 0) { sm[wid] = m; ss[wid] = s; }
    __syncthreads();
    if (tid == 0) {
        float M = sm[0], S = ss[0];
        for (int i = 1; i < 4; ++i)
            if (ss[i] > 0.f) msmerge(M, S, sm[i], ss[i]);
        fin[0] = M;
        fin[1] = logf(S);
    }
    __syncthreads();
    const int i = blockIdx.x * 256 + tid;
    if (i < V) out[i] = ws[OFF_LOG + i] - fin[0] - fin[1];
}

extern "C" void kernel_launch(void* const* d_in, const int* in_sizes, int n_in,
                              void* d_out, int out_size, void* d_ws, size_t ws_size,
                              hipStream_t stream) {
    const long long* idx  = (const long long*)d_in[0];
    const float* hid    = (const float*)d_in[1];
    const float* enc    = (const float*)d_in[2];
    const float* emb    = (const float*)d_in[3];
    const float* attn_W = (const float*)d_in[4];
    const float* attn_b = (const float*)d_in[5];
    const float* comb_W = (const float*)d_in[6];
    const float* comb_b = (const float*)d_in[7];
    const float* w_ih   = (const float*)d_in[8];
    const float* w_hh   = (const float*)d_in[9];
    const float* b_ih   = (const float*)d_in[10];
    const float* b_hh   = (const float*)d_in[11];
    const float* out_W  = (const float*)d_in[12];
    const float* out_b  = (const float*)d_in[13];
    float* out = (float*)d_out;
    float* ws  = (float*)d_ws;

    kA<<<1088, 256, 0, stream>>>(idx, hid, emb, attn_W, attn_b, w_hh, b_hh,
                                 comb_W, ws);
    kB<<<256, 256, 0, stream>>>(enc, comb_W, comb_b, ws, out);
    kC<<<256, 768, 0, stream>>>(w_ih, b_ih, hid, ws, out);
    kD<<<NBLKD, 512, 0, stream>>>(out_W, out_b, out + V, ws);
    kE<<<(V + 255) / 256, 256, 0, stream>>>(ws, out);
}

// Round 15
// 56.268 us; speedup vs baseline: 1.0605x; 1.0605x over previous
//
#include <hip/hip_runtime.h>
#include <math.h>

constexpr int H = 1024;
constexpr int V = 50257;
constexpr int L = 64;

constexpr int NBLKD = 512;             // out-proj blocks (2/CU, one generation)

// ws float offsets
constexpr int OFF_ALOG = 0;            // 64 attention logits
constexpr int OFF_GH   = 64;           // 3072: gh = w_hh@h0 + b_hh
constexpr int OFF_CP   = 64 + 3 * H;   // 1024: comb emb-half partial
constexpr int OFF_X    = OFF_CP + H;   // 1024: x = relu(comb)
constexpr int OFF_LOG  = OFF_X + H;    // V logits
constexpr int OFF_PAIR = OFF_LOG + V;  // 2*NBLKD (m,s) pairs

__device__ __forceinline__ float wsum(float v) {
#pragma unroll
    for (int off = 32; off > 0; off >>= 1) v += __shfl_xor(v, off);
    return v;
}
__device__ __forceinline__ float wmax(float v) {
#pragma unroll
    for (int off = 32; off > 0; off >>= 1) v = fmaxf(v, __shfl_xor(v, off));
    return v;
}

__device__ __forceinline__ float dot4(float4 a, float4 b) {
    return a.x * b.x + a.y * b.y + a.z * b.z + a.w * b.w;
}

__device__ __forceinline__ float dotN(const float* __restrict__ w,
                                      const float* __restrict__ v,
                                      int lane, int n4) { // n4 = N/256
    const float4* w4 = reinterpret_cast<const float4*>(w);
    const float4* v4 = reinterpret_cast<const float4*>(v);
    float acc = 0.f;
    for (int it = 0; it < n4; ++it)
        acc += dot4(w4[lane + it * 64], v4[lane + it * 64]);
    return acc;
}

__device__ __forceinline__ void msmerge(float& m, float& s, float m2, float s2) {
    const float M = fmaxf(m, m2);
    s = s * expf(m - M) + s2 * expf(m2 - M);
    m = M;
}

// ---- A: logits (blocks 0..63) || gh (64..831) || comb-emb-half (832..1087) -
__global__ __launch_bounds__(256) void kA(const long long* __restrict__ idx_p,
                                          const float* __restrict__ hid,
                                          const float* __restrict__ emb,
                                          const float* __restrict__ attn_W,
                                          const float* __restrict__ attn_b,
                                          const float* __restrict__ w_hh,
                                          const float* __restrict__ b_hh,
                                          const float* __restrict__ comb_W,
                                          float* __restrict__ ws) {
    const int tid = threadIdx.x;
    const int lane = tid & 63, wid = tid >> 6;
    const int b = blockIdx.x;
    if (b < 64) {
        const int l = b;
        const int idx = (int)idx_p[0];
        const float4* w4 = reinterpret_cast<const float4*>(attn_W + (size_t)l * (2 * H));
        const float4* e4 = reinterpret_cast<const float4*>(emb + (size_t)idx * H);
        const float4* h4 = reinterpret_cast<const float4*>(hid);
        float acc = dot4(w4[tid], e4[tid]) + dot4(w4[tid + 256], h4[tid]);
        acc = wsum(acc);
        __shared__ float sred[4];
        if (lane == 0) sred[wid] = acc;
        __syncthreads();
        if (tid == 0)
            ws[OFF_ALOG + l] = sred[0] + sred[1] + sred[2] + sred[3] + attn_b[l];
    } else if (b < 832) {
        __shared__ __align__(16) float4 sv[256];
        sv[tid] = reinterpret_cast<const float4*>(hid)[tid];
        __syncthreads();
        const int row = (b - 64) * 4 + wid;  // 0..3071
        float acc = wsum(dotN(w_hh + (size_t)row * H,
                              reinterpret_cast<const float*>(sv), lane, 4));
        if (lane == 0) ws[OFF_GH + row] = acc + b_hh[row];
    } else {
        __shared__ __align__(16) float4 se[256];
        const int idx = (int)idx_p[0];
        se[tid] = reinterpret_cast<const float4*>(emb + (size_t)idx * H)[tid];
        __syncthreads();
        const int row = (b - 832) * 4 + wid;  // 0..1023
        float acc = wsum(dotN(comb_W + (size_t)row * (2 * H),
                              reinterpret_cast<const float*>(se), lane, 4));
        if (lane == 0) ws[OFF_CP + row] = acc;   // no bias yet
    }
}

// ---- B: softmax + attn_applied + comb-attn-half -> x (256 blocks) ---------
__global__ __launch_bounds__(256) void kB(const float* __restrict__ enc,
                                          const float* __restrict__ comb_W,
                                          const float* __restrict__ comb_b,
                                          float* __restrict__ ws,
                                          float* __restrict__ out) {
    __shared__ float wls[L];
    __shared__ __align__(16) float4 sx[256];  // attn_applied
    const int tid = threadIdx.x;
    if (tid < L) {
        const float lg = ws[OFF_ALOG + tid];   // wave 0 holds all 64 logits
        const float m = wmax(lg);
        const float e = expf(lg - m);
        const float s = wsum(e);
        wls[tid] = e / s;
        if (blockIdx.x == 0) out[V + H + tid] = e / s;
    }
    __syncthreads();
    {
        const float4* e4 = reinterpret_cast<const float4*>(enc);
        float4 a4 = {0.f, 0.f, 0.f, 0.f};
#pragma unroll 8
        for (int l = 0; l < L; ++l) {
            const float wl = wls[l];
            const float4 v = e4[l * 256 + tid];
            a4.x += wl * v.x; a4.y += wl * v.y;
            a4.z += wl * v.z; a4.w += wl * v.w;
        }
        sx[tid] = a4;
    }
    __syncthreads();
    const int lane = tid & 63, wid = tid >> 6;
    const int row = blockIdx.x * 4 + wid;  // 0..1023
    float acc = wsum(dotN(comb_W + (size_t)row * (2 * H) + H,
                          reinterpret_cast<const float*>(sx), lane, 4));
    if (lane == 0)
        ws[OFF_X + row] = fmaxf(acc + ws[OFF_CP + row] + comb_b[row], 0.f);
}

// ---- C: gi GEMV + GRU gates fused (256 blocks x 768 threads) --------------
__global__ __launch_bounds__(768) void kC(const float* __restrict__ w_ih,
                                          const float* __restrict__ b_ih,
                                          const float* __restrict__ hid,
                                          float* __restrict__ ws,
                                          float* __restrict__ out) {
    __shared__ __align__(16) float4 sx4[256];  // x
    __shared__ float gi_s[12];
    const int tid = threadIdx.x;
    if (tid < 256) sx4[tid] = reinterpret_cast<const float4*>(ws + OFF_X)[tid];
    __syncthreads();
    const int lane = tid & 63, wid = tid >> 6;  // wid 0..11
    const int g = wid >> 2, i = wid & 3;
    const int row = g * H + blockIdx.x * 4 + i;
    float acc = wsum(dotN(w_ih + (size_t)row * H,
                          reinterpret_cast<const float*>(sx4), lane, 4));
    if (lane == 0) gi_s[wid] = acc + b_ih[row];
    __syncthreads();
    if (tid < 4) {
        const int t = blockIdx.x * 4 + tid;
        const float ir = gi_s[tid], iz = gi_s[4 + tid], in_ = gi_s[8 + tid];
        const float hr = ws[OFF_GH + t];
        const float hz = ws[OFF_GH + H + t];
        const float hn = ws[OFF_GH + 2 * H + t];
        const float r = 1.f / (1.f + expf(-(ir + hr)));
        const float z = 1.f / (1.f + expf(-(iz + hz)));
        const float n = tanhf(in_ + r * hn);
        out[V + t] = (1.f - z) * n + z * hid[t];
    }
}

// ---- D: out-proj GEMV. h_new in REGISTERS; 2-row pairs; plain loads -------
// (Best measured config: R10, 56.34 us.)
__global__ __launch_bounds__(512, 4) void kD(const float* __restrict__ out_W,
                                             const float* __restrict__ out_b,
                                             const float* __restrict__ hnew,
                                             float* __restrict__ ws) {
    __shared__ float lds_log[104];
    const int tid = threadIdx.x, lane = tid & 63, wid = tid >> 6;  // 8 waves
    const int b = blockIdx.x;
    const int row0 = (int)(((long long)b * V) / NBLKD);
    const int row1 = (int)(((long long)(b + 1) * V) / NBLKD);
    const int nrows = row1 - row0;    // 98 or 99
    // h_new fragment per lane: 16 VGPRs, loaded once (L2 serves duplicates)
    const float4* v4 = reinterpret_cast<const float4*>(hnew);
    const float4 hv0 = v4[lane], hv1 = v4[lane + 64];
    const float4 hv2 = v4[lane + 128], hv3 = v4[lane + 192];
    for (int k = 2 * wid; k < nrows; k += 16) {
        const int r0 = row0 + k;
        const bool has2 = (k + 1) < nrows;
        const int r1 = has2 ? r0 + 1 : r0;
        const float4* a4 = reinterpret_cast<const float4*>(out_W + (size_t)r0 * H);
        const float4* b4 = reinterpret_cast<const float4*>(out_W + (size_t)r1 * H);
        const float4 a0 = a4[lane], a1 = a4[lane + 64];
        const float4 a2 = a4[lane + 128], a3 = a4[lane + 192];
        const float4 b0 = b4[lane], b1 = b4[lane + 64];
        const float4 b2 = b4[lane + 128], b3 = b4[lane + 192];
        float sa = dot4(a0, hv0) + dot4(a1, hv1) + dot4(a2, hv2) + dot4(a3, hv3);
        float sb = dot4(b0, hv0) + dot4(b1, hv1) + dot4(b2, hv2) + dot4(b3, hv3);
        sa = wsum(sa); sb = wsum(sb);
        if (lane == 0) {
            const float l0 = sa + out_b[r0];
            lds_log[k] = l0;
            ws[OFF_LOG + r0] = l0;
            if (has2) {
                const float l1 = sb + out_b[r1];
                lds_log[k + 1] = l1;
                ws[OFF_LOG + r1] = l1;
            }
        }
    }
    __syncthreads();
    if (wid == 0) {  // block (m,s) partial over nrows (<= 99)
        float v0 = (lane < nrows) ? lds_log[lane] : -INFINITY;
        float v1 = (64 + lane < nrows) ? lds_log[64 + lane] : -INFINITY;
        const float m = wmax(fmaxf(v0, v1));
        float e = 0.f;
        if (lane < nrows)      e += expf(v0 - m);
        if (64 + lane < nrows) e += expf(v1 - m);
        const float s = wsum(e);
        if (lane == 0) {
            ws[OFF_PAIR + 2 * b] = m;
            ws[OFF_PAIR + 2 * b + 1] = s;
        }
    }
}

// ---- E: redundant (m,s) combine per block + log-softmax write -------------
__global__ __launch_bounds__(256) void kE(const float* __restrict__ ws,
                                          float* __restrict__ out) {
    const int tid = threadIdx.x, lane = tid & 63, wid = tid >> 6;
    float m = -INFINITY, s = 0.f;
    for (int i = tid; i < NBLKD; i += 256) {  // 2 iterations
        const float mi = ws[OFF_PAIR + 2 * i];
        const float si = ws[OFF_PAIR + 2 * i + 1];
        if (si > 0.f) msmerge(m, s, mi, si);
    }
#pragma unroll
    for (int off = 32; off > 0; off >>= 1) {
        const float mo = __shfl_xor(m, off);
        const float so = __shfl_xor(s, off);
        if (so > 0.f) msmerge(m, s, mo, so);
    }
    __shared__ float sm[4], ss[4], fin[2];
    if (lane == 0) { sm[wid] = m; ss[wid] = s; }
    __syncthreads();
    if (tid == 0) {
        float M = sm[0], S = ss[0];
        for (int i = 1; i < 4; ++i)
            if (ss[i] > 0.f) msmerge(M, S, sm[i], ss[i]);
        fin[0] = M;
        fin[1] = logf(S);
    }
    __syncthreads();
    const int i = blockIdx.x * 256 + tid;
    if (i < V) out[i] = ws[OFF_LOG + i] - fin[0] - fin[1];
}

extern "C" void kernel_launch(void* const* d_in, const int* in_sizes, int n_in,
                              void* d_out, int out_size, void* d_ws, size_t ws_size,
                              hipStream_t stream) {
    const long long* idx  = (const long long*)d_in[0];
    const float* hid    = (const float*)d_in[1];
    const float* enc    = (const float*)d_in[2];
    const float* emb    = (const float*)d_in[3];
    const float* attn_W = (const float*)d_in[4];
    const float* attn_b = (const float*)d_in[5];
    const float* comb_W = (const float*)d_in[6];
    const float* comb_b = (const float*)d_in[7];
    const float* w_ih   = (const float*)d_in[8];
    const float* w_hh   = (const float*)d_in[9];
    const float* b_ih   = (const float*)d_in[10];
    const float* b_hh   = (const float*)d_in[11];
    const float* out_W  = (const float*)d_in[12];
    const float* out_b  = (const float*)d_in[13];
    float* out = (float*)d_out;
    float* ws  = (float*)d_ws;

    kA<<<1088, 256, 0, stream>>>(idx, hid, emb, attn_W, attn_b, w_hh, b_hh,
                                 comb_W, ws);
    kB<<<256, 256, 0, stream>>>(enc, comb_W, comb_b, ws, out);
    kC<<<256, 768, 0, stream>>>(w_ih, b_ih, hid, ws, out);
    kD<<<NBLKD, 512, 0, stream>>>(out_W, out_b, out + V, ws);
    kE<<<(V + 255) / 256, 256, 0, stream>>>(ws, out);
}